// Round 9
// baseline (438.267 us; speedup 1.0000x reference)
//
#include <hip/hip_runtime.h>
#include <math.h>

// ---------------------------------------------------------------------------
// 2-layer GAT (PyG GATConv semantics) on MI355X.
// R6: CSR via LDS-atomic bucket sort (no global atomics).
// R5: layer-2 commuted with W2 (aggregate 64-dim hrelu).
// R8: true 8-deep gather MLP (phase-split shfl/load/fma, register arrays),
//     gemm_out fused into agg2 epilogue (u never materialized),
//     w2a fused into hist.  (R9 resubmission — R8 never ran: GPU timeout.)
// ---------------------------------------------------------------------------

#define SORT_EPB 4096   // edges per hist/scatter block (256 thr x 16)

static __device__ __forceinline__ float lrelu(float v) {
    return v > 0.f ? v : 0.2f * v;
}

// ----------------------------- scan machinery ------------------------------
// Block-level exclusive scan: each block scans 1024 elements (4/thread).
__global__ __launch_bounds__(256) void k_scan_blocks(const int* __restrict__ deg,
                                                     int* __restrict__ offs,
                                                     int* __restrict__ bsum, int N) {
    __shared__ int ls[256];
    const int t = threadIdx.x;
    const int base = blockIdx.x * 1024 + t * 4;
    int v0 = (base + 0 < N) ? deg[base + 0] : 0;
    int v1 = (base + 1 < N) ? deg[base + 1] : 0;
    int v2 = (base + 2 < N) ? deg[base + 2] : 0;
    int v3 = (base + 3 < N) ? deg[base + 3] : 0;
    const int sum = v0 + v1 + v2 + v3;
    int val = sum;
    ls[t] = val;
    __syncthreads();
    for (int off = 1; off < 256; off <<= 1) {
        int x = (t >= off) ? ls[t - off] : 0;
        __syncthreads();
        val += x;
        ls[t] = val;
        __syncthreads();
    }
    int run = val - sum;  // exclusive prefix of this thread's chunk
    if (base + 0 < N) offs[base + 0] = run;  run += v0;
    if (base + 1 < N) offs[base + 1] = run;  run += v1;
    if (base + 2 < N) offs[base + 2] = run;  run += v2;
    if (base + 3 < N) offs[base + 3] = run;
    if (t == 255) bsum[blockIdx.x] = val;    // block total
}

// Parallel exclusive scan of block sums (B <= 256).
__global__ __launch_bounds__(256) void k_scan_tops(int* __restrict__ bsum, int B) {
    __shared__ int ls[256];
    const int t = threadIdx.x;
    int v = (t < B) ? bsum[t] : 0;
    int val = v;
    ls[t] = val;
    __syncthreads();
    for (int off = 1; off < 256; off <<= 1) {
        int x = (t >= off) ? ls[t - off] : 0;
        __syncthreads();
        val += x;
        ls[t] = val;
        __syncthreads();
    }
    if (t < B) bsum[t] = val - v;            // exclusive
}

__global__ __launch_bounds__(256) void k_scan_add(int* __restrict__ offs,
                                                  const int* __restrict__ bsum,
                                                  int N, int E) {
    int i = blockIdx.x * 256 + threadIdx.x;
    if (i < N) offs[i] = offs[i] + bsum[i >> 10];
    if (i == 0) offs[N] = E;                 // sentinel
}

// ----------------------- bucket-sort CSR build (LDS only) ------------------
// Pass A: per-block histogram of high bits (dst>>9), NB2 bins (<=256).
// Extra tail block (blockIdx == SB) computes w2as/w2ad = W2 @ a_s2 / a_d2.
__global__ __launch_bounds__(256) void k_hist(const int* __restrict__ dst,
                                              int* __restrict__ counts,
                                              int E, int B, int NB2,
                                              const float* __restrict__ W2,
                                              const float* __restrict__ as2,
                                              const float* __restrict__ ad2,
                                              float* __restrict__ w2as,
                                              float* __restrict__ w2ad) {
    const int t = threadIdx.x;
    const int b = blockIdx.x;
    if (b == B) {                            // tiny w2a precompute
        if (t < 64) {
            const float* row = W2 + t * 128;
            float s = 0.f, d = 0.f;
            #pragma unroll 8
            for (int j = 0; j < 128; ++j) { s = fmaf(row[j], as2[j], s); d = fmaf(row[j], ad2[j], d); }
            w2as[t] = s; w2ad[t] = d;
        }
        return;
    }
    __shared__ int h[256];
    h[t] = 0;
    __syncthreads();
    const int base_i = b * SORT_EPB;
    #pragma unroll 4
    for (int k = 0; k < 16; ++k) {
        int i = base_i + k * 256 + t;
        if (i < E) atomicAdd(&h[dst[i] >> 9], 1);
    }
    __syncthreads();
    if (t < NB2) counts[t * B + b] = h[t];   // bin-major
}

// Pass B: scatter edges into bucket order; pack (src<<9)|(dst&511).
__global__ __launch_bounds__(256) void k_bucket_scatter(const int* __restrict__ src,
                                                        const int* __restrict__ dst,
                                                        const int* __restrict__ base,
                                                        int* __restrict__ packed,
                                                        int E, int B, int NB2) {
    __shared__ int cur[256];
    const int t = threadIdx.x;
    const int b = blockIdx.x;
    if (t < NB2) cur[t] = base[t * B + b];
    __syncthreads();
    const int base_i = b * SORT_EPB;
    #pragma unroll 4
    for (int k = 0; k < 16; ++k) {
        int i = base_i + k * 256 + t;
        if (i < E) {
            int d = dst[i];
            int pos = atomicAdd(&cur[d >> 9], 1);
            packed[pos] = (src[i] << 9) | (d & 511);
        }
    }
}

// Pass C: per-bucket counting sort (512 nodes/bucket); emits srcs + offs.
__global__ __launch_bounds__(256) void k_bucket_sort(const int* __restrict__ packed,
                                                     const int* __restrict__ base,
                                                     int* __restrict__ srcs,
                                                     int* __restrict__ offs,
                                                     int E, int B, int N) {
    __shared__ int h[512], sc[512], cur[512], ls[256];
    const int t = threadIdx.x;
    const int j = blockIdx.x;
    const int bstart = base[j * B];
    const int bend   = base[(j + 1) * B];    // sentinel handles last bucket
    h[t] = 0; h[t + 256] = 0;
    __syncthreads();
    for (int i = bstart + t; i < bend; i += 256)
        atomicAdd(&h[packed[i] & 511], 1);
    __syncthreads();
    // exclusive scan of 512 bins: thread t owns bins {2t, 2t+1}
    const int a0 = h[2 * t], a1 = h[2 * t + 1];
    int val = a0 + a1;
    ls[t] = val;
    __syncthreads();
    for (int off = 1; off < 256; off <<= 1) {
        int x = (t >= off) ? ls[t - off] : 0;
        __syncthreads();
        val += x;
        ls[t] = val;
        __syncthreads();
    }
    const int pre = val - (a0 + a1);
    sc[2 * t] = pre;         sc[2 * t + 1] = pre + a0;
    cur[2 * t] = pre;        cur[2 * t + 1] = pre + a0;
    __syncthreads();
    // offs: node = j*512 + bin (bijective within bucket; self-loops => dense)
    const int node0 = j * 512 + 2 * t;
    if (node0 < N)     offs[node0]     = bstart + sc[2 * t];
    if (node0 + 1 < N) offs[node0 + 1] = bstart + sc[2 * t + 1];
    if (j == 0 && t == 0) offs[N] = E;
    // scatter within bucket (order within node-segment is arbitrary: OK)
    for (int i = bstart + t; i < bend; i += 256) {
        int p = packed[i];
        int pos = atomicAdd(&cur[p & 511], 1);
        srcs[bstart + pos] = p >> 9;
    }
}

// ----------------------------- GEMM 1: [N,128]x[128,64] --------------------
// 64x64 tile, 4x4 register block/thread; fused s1/d1 epilogue.
__global__ __launch_bounds__(256) void k_gemm1(const float* __restrict__ x,
                                               const float* __restrict__ W,
                                               const float* __restrict__ a_s,
                                               const float* __restrict__ a_d,
                                               float* __restrict__ h,
                                               float* __restrict__ s1,
                                               float* __restrict__ d1, int N) {
    __shared__ float Ws[128 * 64];   // 32 KB, full W
    __shared__ float xs[64][68];
    const int t = threadIdx.x;
    for (int i = t; i < 128 * 64; i += 256) Ws[i] = W[i];
    const int row0 = blockIdx.x * 64;
    const int tc = (t & 15) * 4;    // 16 col groups
    const int tr = (t >> 4) * 4;    // 16 row groups
    float acc[4][4] = {};
    for (int kb = 0; kb < 128; kb += 64) {
        if (kb) __syncthreads();
        for (int i = t; i < 1024; i += 256) {       // 64 rows x 16 float4
            int r = i >> 4, c = i & 15;
            float4 v = make_float4(0.f, 0.f, 0.f, 0.f);
            if (row0 + r < N)
                v = *(const float4*)(x + (size_t)(row0 + r) * 128 + kb + c * 4);
            *(float4*)&xs[r][c * 4] = v;
        }
        __syncthreads();
        #pragma unroll 4
        for (int k = 0; k < 64; k += 4) {
            const float4 xv0 = *(const float4*)&xs[tr + 0][k];
            const float4 xv1 = *(const float4*)&xs[tr + 1][k];
            const float4 xv2 = *(const float4*)&xs[tr + 2][k];
            const float4 xv3 = *(const float4*)&xs[tr + 3][k];
            #pragma unroll
            for (int kk = 0; kk < 4; ++kk) {
                const float4 w = *(const float4*)&Ws[(kb + k + kk) * 64 + tc];
                const float a0 = (&xv0.x)[kk], a1 = (&xv1.x)[kk];
                const float a2 = (&xv2.x)[kk], a3 = (&xv3.x)[kk];
                acc[0][0] = fmaf(a0, w.x, acc[0][0]); acc[0][1] = fmaf(a0, w.y, acc[0][1]);
                acc[0][2] = fmaf(a0, w.z, acc[0][2]); acc[0][3] = fmaf(a0, w.w, acc[0][3]);
                acc[1][0] = fmaf(a1, w.x, acc[1][0]); acc[1][1] = fmaf(a1, w.y, acc[1][1]);
                acc[1][2] = fmaf(a1, w.z, acc[1][2]); acc[1][3] = fmaf(a1, w.w, acc[1][3]);
                acc[2][0] = fmaf(a2, w.x, acc[2][0]); acc[2][1] = fmaf(a2, w.y, acc[2][1]);
                acc[2][2] = fmaf(a2, w.z, acc[2][2]); acc[2][3] = fmaf(a2, w.w, acc[2][3]);
                acc[3][0] = fmaf(a3, w.x, acc[3][0]); acc[3][1] = fmaf(a3, w.y, acc[3][1]);
                acc[3][2] = fmaf(a3, w.z, acc[3][2]); acc[3][3] = fmaf(a3, w.w, acc[3][3]);
            }
        }
    }
    #pragma unroll
    for (int i = 0; i < 4; ++i) {
        int r = row0 + tr + i;
        if (r < N)
            *(float4*)(h + (size_t)r * 64 + tc) =
                make_float4(acc[i][0], acc[i][1], acc[i][2], acc[i][3]);
    }
    // fused s1/d1: cols [tc,tc+3] lie inside head tc>>3; pair (t^1) completes it.
    const float as0 = a_s[tc + 0], as1v = a_s[tc + 1], as2v = a_s[tc + 2], as3 = a_s[tc + 3];
    const float ad0 = a_d[tc + 0], ad1v = a_d[tc + 1], ad2v = a_d[tc + 2], ad3 = a_d[tc + 3];
    #pragma unroll
    for (int i = 0; i < 4; ++i) {
        float ps = acc[i][0] * as0 + acc[i][1] * as1v + acc[i][2] * as2v + acc[i][3] * as3;
        float pd = acc[i][0] * ad0 + acc[i][1] * ad1v + acc[i][2] * ad2v + acc[i][3] * ad3;
        ps += __shfl_xor(ps, 1);
        pd += __shfl_xor(pd, 1);
        int r = row0 + tr + i;
        if ((t & 1) == 0 && r < N) {
            int hh = (t & 15) >> 1;
            s1[r * 8 + hh] = ps;
            d1[r * 8 + hh] = pd;
        }
    }
}

// ------------------- layer-1 aggregation (8 heads x 8 dims) ----------------
// One wave per destination node. Phase-split inner loop: all shfls -> all 8
// loads (register array, true MLP depth 8) -> all fmas.
__global__ __launch_bounds__(256) void k_agg1(const float* __restrict__ h1,
                                              const float* __restrict__ s1,
                                              const float* __restrict__ d1,
                                              const int* __restrict__ offs,
                                              const int* __restrict__ srcs,
                                              const float* __restrict__ bias,
                                              const float* __restrict__ w2as,
                                              const float* __restrict__ w2ad,
                                              float* __restrict__ out,
                                              float* __restrict__ s2,
                                              float* __restrict__ d2, int N) {
    int wid = (blockIdx.x * 256 + threadIdx.x) >> 6;
    int lane = threadIdx.x & 63;
    if (wid >= N) return;
    const int beg = offs[wid], end = offs[wid + 1];
    const int slot = lane >> 3;        // staging: edge slot (8 per group)
    const int hl = lane & 7;           // staging: head
    const int c = lane & 31;           // gather: col pair {2c,2c+1}
    const int half = lane >> 5;        // gather: which edge of a pair
    const int hc = c >> 2;             // head containing cols {2c,2c+1}
    const float dt = d1[wid * 8 + hl];
    float accx = 0.f, accy = 0.f, dsum = 0.f;
    int sa = 0, sb = 0; float exa = 0.f, exb = 0.f;
    if (beg + slot < end)     { sa = srcs[beg + slot];     exa = __expf(lrelu(s1[sa * 8 + hl] + dt)); }
    if (beg + 8 + slot < end) { sb = srcs[beg + 8 + slot]; exb = __expf(lrelu(s1[sb * 8 + hl] + dt)); }
    for (int cb = beg; cb < end; cb += 16) {
        int sna = 0, snb = 0; float exna = 0.f, exnb = 0.f;
        if (cb + 16 + slot < end) { sna = srcs[cb + 16 + slot]; exna = __expf(lrelu(s1[sna * 8 + hl] + dt)); }
        if (cb + 24 + slot < end) { snb = srcs[cb + 24 + slot]; exnb = __expf(lrelu(s1[snb * 8 + hl] + dt)); }
        dsum += exa + exb;
        // phase 1: all cross-lane broadcasts
        int ssA[4], ssB[4]; float eA[4], eB[4];
        #pragma unroll
        for (int p = 0; p < 4; ++p) {
            const int sl = (2 * p + half) * 8;
            eA[p] = __shfl(exa, sl + hc);  ssA[p] = __shfl(sa, sl);
            eB[p] = __shfl(exb, sl + hc);  ssB[p] = __shfl(sb, sl);
        }
        // phase 2: 8 independent gather loads in flight
        float2 hA[4], hB[4];
        #pragma unroll
        for (int p = 0; p < 4; ++p) {
            hA[p] = *(const float2*)(h1 + (size_t)ssA[p] * 64 + 2 * c);
            hB[p] = *(const float2*)(h1 + (size_t)ssB[p] * 64 + 2 * c);
        }
        // phase 3: accumulate
        #pragma unroll
        for (int p = 0; p < 4; ++p) {
            accx = fmaf(hA[p].x, eA[p], accx); accy = fmaf(hA[p].y, eA[p], accy);
            accx = fmaf(hB[p].x, eB[p], accx); accy = fmaf(hB[p].y, eB[p], accy);
        }
        sa = sna; exa = exna; sb = snb; exb = exnb;
    }
    accx += __shfl_xor(accx, 32);
    accy += __shfl_xor(accy, 32);
    dsum += __shfl_xor(dsum, 8);
    dsum += __shfl_xor(dsum, 16);
    dsum += __shfl_xor(dsum, 32);
    const float denom = __shfl(dsum, hc);
    float ox = 0.f, oy = 0.f;
    if (half == 0) {
        const float2 bv = *(const float2*)(bias + 2 * c);
        ox = fmaxf(accx / denom + bv.x, 0.f);    // fused inter-layer ReLU
        oy = fmaxf(accy / denom + bv.y, 0.f);
        *(float2*)(out + (size_t)wid * 64 + 2 * c) = make_float2(ox, oy);
    }
    // layer-2 logit terms: s2 = row . w2as, d2 = row . w2ad
    float ps = 0.f, pd = 0.f;
    if (half == 0) {
        const float2 was = *(const float2*)(w2as + 2 * c);
        const float2 wad = *(const float2*)(w2ad + 2 * c);
        ps = ox * was.x + oy * was.y;
        pd = ox * wad.x + oy * wad.y;
    }
    #pragma unroll
    for (int mask = 1; mask < 32; mask <<= 1) {
        ps += __shfl_xor(ps, mask);
        pd += __shfl_xor(pd, mask);
    }
    if (lane == 0) { s2[wid] = ps; d2[wid] = pd; }
}

// -------- layer-2 aggregation over hrelu + FUSED out = u @ W2 + b2 ---------
// One wave per destination node. Phase-split gather (8 loads in flight).
// Epilogue: u (64) lives across lanes; 32 shfl-broadcasts x coalesced L1-hot
// W2 row reads produce out[wid, 0..127] directly. u never hits memory.
__global__ __launch_bounds__(256) void k_agg2(const float* __restrict__ hrelu,
                                              const float* __restrict__ s2,
                                              const float* __restrict__ d2,
                                              const int* __restrict__ offs,
                                              const int* __restrict__ srcs,
                                              const float* __restrict__ W2,
                                              const float* __restrict__ b2,
                                              float* __restrict__ out, int N) {
    int wid = (blockIdx.x * 256 + threadIdx.x) >> 6;
    int lane = threadIdx.x & 63;
    if (wid >= N) return;
    const int beg = offs[wid], end = offs[wid + 1];
    const int c = lane & 31;
    const int half = lane >> 5;
    const float dn = d2[wid];
    float accx = 0.f, accy = 0.f, dsum = 0.f;
    int s_cur = 0; float ex_cur = 0.f;
    if (beg + lane < end) {
        s_cur = srcs[beg + lane];
        ex_cur = __expf(lrelu(s2[s_cur] + dn));            // no max-shift
    }
    for (int cb = beg; cb < end; cb += 64) {
        int sn = 0; float exn = 0.f;
        if (cb + 64 + lane < end) { sn = srcs[cb + 64 + lane]; exn = __expf(lrelu(s2[sn] + dn)); }
        dsum += ex_cur;
        const int npairs = (min(64, end - cb) + 1) >> 1;
        for (int p0 = 0; p0 < npairs; p0 += 8) {
            // phase 1: broadcasts
            int ss[8]; float e[8];
            #pragma unroll
            for (int q = 0; q < 8; ++q) {
                const int sl = min(2 * (p0 + q) + half, 63);  // padded slots have ex=0
                e[q] = __shfl(ex_cur, sl);
                ss[q] = __shfl(s_cur, sl);
            }
            // phase 2: 8 independent loads
            float2 hv[8];
            #pragma unroll
            for (int q = 0; q < 8; ++q)
                hv[q] = *(const float2*)(hrelu + (size_t)ss[q] * 64 + 2 * c);
            // phase 3: accumulate
            #pragma unroll
            for (int q = 0; q < 8; ++q) {
                accx = fmaf(hv[q].x, e[q], accx);
                accy = fmaf(hv[q].y, e[q], accy);
            }
        }
        s_cur = sn; ex_cur = exn;
    }
    accx += __shfl_xor(accx, 32);      // both halves now hold u-sums for cols {2c,2c+1}
    accy += __shfl_xor(accy, 32);
    #pragma unroll
    for (int mask = 1; mask < 64; mask <<= 1) dsum += __shfl_xor(dsum, mask);
    const float inv = 1.f / dsum;
    const float ux = accx * inv;       // u[2c]  (valid on all lanes)
    const float uy = accy * inv;       // u[2c+1]
    // fused final GEMM: lane handles output dims {lane, lane+64}
    float o0 = 0.f, o1 = 0.f;
    #pragma unroll 8
    for (int k2 = 0; k2 < 32; ++k2) {
        const float vx = __shfl(ux, k2);           // u[2*k2]
        const float vy = __shfl(uy, k2);           // u[2*k2+1]
        const float* w0 = W2 + (2 * k2) * 128;     // rows 2k2, 2k2+1 (L1-hot)
        o0 = fmaf(vx, w0[lane], o0);
        o1 = fmaf(vx, w0[lane + 64], o1);
        o0 = fmaf(vy, w0[128 + lane], o0);
        o1 = fmaf(vy, w0[128 + lane + 64], o1);
    }
    out[(size_t)wid * 128 + lane]      = o0 + b2[lane];
    out[(size_t)wid * 128 + 64 + lane] = o1 + b2[lane + 64];
}

// ---------------------------------------------------------------------------

extern "C" void kernel_launch(void* const* d_in, const int* in_sizes, int n_in,
                              void* d_out, int out_size, void* d_ws, size_t ws_size,
                              hipStream_t stream) {
    const float* x   = (const float*)d_in[0];
    const int*   ei  = (const int*)d_in[1];
    const float* W1  = (const float*)d_in[2];
    const float* as1 = (const float*)d_in[3];
    const float* ad1 = (const float*)d_in[4];
    const float* b1  = (const float*)d_in[5];
    const float* W2  = (const float*)d_in[6];
    const float* as2 = (const float*)d_in[7];
    const float* ad2 = (const float*)d_in[8];
    const float* b2  = (const float*)d_in[9];
    float* out = (float*)d_out;

    const int N = in_sizes[0] / 128;   // 100000
    const int E = in_sizes[1] / 2;     // 1700000
    const int* srcp = ei;
    const int* dstp = ei + E;

    const int SB  = (E + SORT_EPB - 1) / SORT_EPB;   // sort blocks (416)
    const int NB2 = (N + 511) >> 9;                  // high-bit buckets (196)
    const int L   = NB2 * SB;                        // counts length

    // workspace carve-out (aligned to 256B)
    char* w = (char*)d_ws;
    auto carve = [&](size_t bytes) -> char* {
        char* p = w;
        w += (bytes + 255) & ~(size_t)255;
        return p;
    };
    float* h1    = (float*)carve((size_t)N * 64 * 4);
    float* hrelu = (float*)carve((size_t)N * 64 * 4);
    float* s1    = (float*)carve((size_t)N * 8 * 4);
    float* d1    = (float*)carve((size_t)N * 8 * 4);
    float* s2    = (float*)carve((size_t)N * 4);
    float* d2    = (float*)carve((size_t)N * 4);
    float* w2as  = (float*)carve(64 * 4);
    float* w2ad  = (float*)carve(64 * 4);
    int*   offs  = (int*)carve((size_t)(N + 1) * 4);
    int*   counts= (int*)carve((size_t)(L + 1) * 4);
    const int BS = (L + 1023) / 1024;                // scan blocks for counts
    int*   bsum  = (int*)carve((size_t)BS * 4);
    int*   packed= (int*)carve((size_t)E * 4);
    int*   srcs  = (int*)carve((size_t)E * 4);
    (void)ws_size; (void)n_in; (void)out_size;

    const int TB = 256;
    // --- CSR build: LDS-atomic bucket sort (no global atomics) + w2a tail ---
    hipLaunchKernelGGL(k_hist,           dim3(SB + 1), dim3(TB), 0, stream,
                       dstp, counts, E, SB, NB2, W2, as2, ad2, w2as, w2ad);
    hipLaunchKernelGGL(k_scan_blocks,    dim3(BS), dim3(TB), 0, stream, counts, counts, bsum, L);
    hipLaunchKernelGGL(k_scan_tops,      dim3(1),  dim3(TB), 0, stream, bsum, BS);
    hipLaunchKernelGGL(k_scan_add,       dim3((L + TB - 1) / TB), dim3(TB), 0, stream, counts, bsum, L, E);
    hipLaunchKernelGGL(k_bucket_scatter, dim3(SB), dim3(TB), 0, stream, srcp, dstp, counts, packed, E, SB, NB2);
    hipLaunchKernelGGL(k_bucket_sort,    dim3(NB2), dim3(TB), 0, stream, packed, counts, srcs, offs, E, SB, N);
    // --- layer 1 ---
    hipLaunchKernelGGL(k_gemm1, dim3((N + 63) / 64), dim3(TB), 0, stream, x, W1, as1, ad1, h1, s1, d1, N);
    hipLaunchKernelGGL(k_agg1,  dim3((N + 3) / 4),   dim3(TB), 0, stream,
                       h1, s1, d1, offs, srcs, b1, w2as, w2ad, hrelu, s2, d2, N);
    // --- layer 2: aggregate hrelu with fused final GEMM ---
    hipLaunchKernelGGL(k_agg2, dim3((N + 3) / 4), dim3(TB), 0, stream,
                       hrelu, s2, d2, offs, srcs, W2, b2, out, N);
}

// Round 10
// 396.250 us; speedup vs baseline: 1.1060x; 1.1060x over previous
//
#include <hip/hip_runtime.h>
#include <math.h>

// ---------------------------------------------------------------------------
// 2-layer GAT (PyG GATConv semantics) on MI355X.
// R6: CSR via LDS-atomic bucket sort (no global atomics).
// R5: layer-2 commuted with W2 (aggregate 64-dim hrelu).
// R10: REVERT agg2+gemm_out fusion (R9: serial per-wave GEMM tail, +75us).
//      Force true 8-deep gather MLP with sched_barrier(0) fences (R9's
//      register arrays were re-serialized by the scheduler; VGPR stayed 32).
// ---------------------------------------------------------------------------

#define SORT_EPB 4096   // edges per hist/scatter block (256 thr x 16)

static __device__ __forceinline__ float lrelu(float v) {
    return v > 0.f ? v : 0.2f * v;
}

// ----------------------------- scan machinery ------------------------------
// Block-level exclusive scan: each block scans 1024 elements (4/thread).
__global__ __launch_bounds__(256) void k_scan_blocks(const int* __restrict__ deg,
                                                     int* __restrict__ offs,
                                                     int* __restrict__ bsum, int N) {
    __shared__ int ls[256];
    const int t = threadIdx.x;
    const int base = blockIdx.x * 1024 + t * 4;
    int v0 = (base + 0 < N) ? deg[base + 0] : 0;
    int v1 = (base + 1 < N) ? deg[base + 1] : 0;
    int v2 = (base + 2 < N) ? deg[base + 2] : 0;
    int v3 = (base + 3 < N) ? deg[base + 3] : 0;
    const int sum = v0 + v1 + v2 + v3;
    int val = sum;
    ls[t] = val;
    __syncthreads();
    for (int off = 1; off < 256; off <<= 1) {
        int x = (t >= off) ? ls[t - off] : 0;
        __syncthreads();
        val += x;
        ls[t] = val;
        __syncthreads();
    }
    int run = val - sum;  // exclusive prefix of this thread's chunk
    if (base + 0 < N) offs[base + 0] = run;  run += v0;
    if (base + 1 < N) offs[base + 1] = run;  run += v1;
    if (base + 2 < N) offs[base + 2] = run;  run += v2;
    if (base + 3 < N) offs[base + 3] = run;
    if (t == 255) bsum[blockIdx.x] = val;    // block total
}

// Parallel exclusive scan of block sums (B <= 256).
__global__ __launch_bounds__(256) void k_scan_tops(int* __restrict__ bsum, int B) {
    __shared__ int ls[256];
    const int t = threadIdx.x;
    int v = (t < B) ? bsum[t] : 0;
    int val = v;
    ls[t] = val;
    __syncthreads();
    for (int off = 1; off < 256; off <<= 1) {
        int x = (t >= off) ? ls[t - off] : 0;
        __syncthreads();
        val += x;
        ls[t] = val;
        __syncthreads();
    }
    if (t < B) bsum[t] = val - v;            // exclusive
}

__global__ __launch_bounds__(256) void k_scan_add(int* __restrict__ offs,
                                                  const int* __restrict__ bsum,
                                                  int N, int E) {
    int i = blockIdx.x * 256 + threadIdx.x;
    if (i < N) offs[i] = offs[i] + bsum[i >> 10];
    if (i == 0) offs[N] = E;                 // sentinel
}

// ----------------------- bucket-sort CSR build (LDS only) ------------------
// Pass A: per-block histogram of high bits (dst>>9), NB2 bins (<=256).
// Extra tail block (blockIdx == SB) computes w2as/w2ad = W2 @ a_s2 / a_d2.
__global__ __launch_bounds__(256) void k_hist(const int* __restrict__ dst,
                                              int* __restrict__ counts,
                                              int E, int B, int NB2,
                                              const float* __restrict__ W2,
                                              const float* __restrict__ as2,
                                              const float* __restrict__ ad2,
                                              float* __restrict__ w2as,
                                              float* __restrict__ w2ad) {
    const int t = threadIdx.x;
    const int b = blockIdx.x;
    if (b == B) {                            // tiny w2a precompute
        if (t < 64) {
            const float* row = W2 + t * 128;
            float s = 0.f, d = 0.f;
            #pragma unroll 8
            for (int j = 0; j < 128; ++j) { s = fmaf(row[j], as2[j], s); d = fmaf(row[j], ad2[j], d); }
            w2as[t] = s; w2ad[t] = d;
        }
        return;
    }
    __shared__ int h[256];
    h[t] = 0;
    __syncthreads();
    const int base_i = b * SORT_EPB;
    #pragma unroll 4
    for (int k = 0; k < 16; ++k) {
        int i = base_i + k * 256 + t;
        if (i < E) atomicAdd(&h[dst[i] >> 9], 1);
    }
    __syncthreads();
    if (t < NB2) counts[t * B + b] = h[t];   // bin-major
}

// Pass B: scatter edges into bucket order; pack (src<<9)|(dst&511).
__global__ __launch_bounds__(256) void k_bucket_scatter(const int* __restrict__ src,
                                                        const int* __restrict__ dst,
                                                        const int* __restrict__ base,
                                                        int* __restrict__ packed,
                                                        int E, int B, int NB2) {
    __shared__ int cur[256];
    const int t = threadIdx.x;
    const int b = blockIdx.x;
    if (t < NB2) cur[t] = base[t * B + b];
    __syncthreads();
    const int base_i = b * SORT_EPB;
    #pragma unroll 4
    for (int k = 0; k < 16; ++k) {
        int i = base_i + k * 256 + t;
        if (i < E) {
            int d = dst[i];
            int pos = atomicAdd(&cur[d >> 9], 1);
            packed[pos] = (src[i] << 9) | (d & 511);
        }
    }
}

// Pass C: per-bucket counting sort (512 nodes/bucket); emits srcs + offs.
__global__ __launch_bounds__(256) void k_bucket_sort(const int* __restrict__ packed,
                                                     const int* __restrict__ base,
                                                     int* __restrict__ srcs,
                                                     int* __restrict__ offs,
                                                     int E, int B, int N) {
    __shared__ int h[512], sc[512], cur[512], ls[256];
    const int t = threadIdx.x;
    const int j = blockIdx.x;
    const int bstart = base[j * B];
    const int bend   = base[(j + 1) * B];    // sentinel handles last bucket
    h[t] = 0; h[t + 256] = 0;
    __syncthreads();
    for (int i = bstart + t; i < bend; i += 256)
        atomicAdd(&h[packed[i] & 511], 1);
    __syncthreads();
    // exclusive scan of 512 bins: thread t owns bins {2t, 2t+1}
    const int a0 = h[2 * t], a1 = h[2 * t + 1];
    int val = a0 + a1;
    ls[t] = val;
    __syncthreads();
    for (int off = 1; off < 256; off <<= 1) {
        int x = (t >= off) ? ls[t - off] : 0;
        __syncthreads();
        val += x;
        ls[t] = val;
        __syncthreads();
    }
    const int pre = val - (a0 + a1);
    sc[2 * t] = pre;         sc[2 * t + 1] = pre + a0;
    cur[2 * t] = pre;        cur[2 * t + 1] = pre + a0;
    __syncthreads();
    // offs: node = j*512 + bin (bijective within bucket; self-loops => dense)
    const int node0 = j * 512 + 2 * t;
    if (node0 < N)     offs[node0]     = bstart + sc[2 * t];
    if (node0 + 1 < N) offs[node0 + 1] = bstart + sc[2 * t + 1];
    if (j == 0 && t == 0) offs[N] = E;
    // scatter within bucket (order within node-segment is arbitrary: OK)
    for (int i = bstart + t; i < bend; i += 256) {
        int p = packed[i];
        int pos = atomicAdd(&cur[p & 511], 1);
        srcs[bstart + pos] = p >> 9;
    }
}

// ----------------------------- GEMM 1: [N,128]x[128,64] --------------------
// 64x64 tile, 4x4 register block/thread; fused s1/d1 epilogue.
__global__ __launch_bounds__(256) void k_gemm1(const float* __restrict__ x,
                                               const float* __restrict__ W,
                                               const float* __restrict__ a_s,
                                               const float* __restrict__ a_d,
                                               float* __restrict__ h,
                                               float* __restrict__ s1,
                                               float* __restrict__ d1, int N) {
    __shared__ float Ws[128 * 64];   // 32 KB, full W
    __shared__ float xs[64][68];
    const int t = threadIdx.x;
    for (int i = t; i < 128 * 64; i += 256) Ws[i] = W[i];
    const int row0 = blockIdx.x * 64;
    const int tc = (t & 15) * 4;    // 16 col groups
    const int tr = (t >> 4) * 4;    // 16 row groups
    float acc[4][4] = {};
    for (int kb = 0; kb < 128; kb += 64) {
        if (kb) __syncthreads();
        for (int i = t; i < 1024; i += 256) {       // 64 rows x 16 float4
            int r = i >> 4, c = i & 15;
            float4 v = make_float4(0.f, 0.f, 0.f, 0.f);
            if (row0 + r < N)
                v = *(const float4*)(x + (size_t)(row0 + r) * 128 + kb + c * 4);
            *(float4*)&xs[r][c * 4] = v;
        }
        __syncthreads();
        #pragma unroll 4
        for (int k = 0; k < 64; k += 4) {
            const float4 xv0 = *(const float4*)&xs[tr + 0][k];
            const float4 xv1 = *(const float4*)&xs[tr + 1][k];
            const float4 xv2 = *(const float4*)&xs[tr + 2][k];
            const float4 xv3 = *(const float4*)&xs[tr + 3][k];
            #pragma unroll
            for (int kk = 0; kk < 4; ++kk) {
                const float4 w = *(const float4*)&Ws[(kb + k + kk) * 64 + tc];
                const float a0 = (&xv0.x)[kk], a1 = (&xv1.x)[kk];
                const float a2 = (&xv2.x)[kk], a3 = (&xv3.x)[kk];
                acc[0][0] = fmaf(a0, w.x, acc[0][0]); acc[0][1] = fmaf(a0, w.y, acc[0][1]);
                acc[0][2] = fmaf(a0, w.z, acc[0][2]); acc[0][3] = fmaf(a0, w.w, acc[0][3]);
                acc[1][0] = fmaf(a1, w.x, acc[1][0]); acc[1][1] = fmaf(a1, w.y, acc[1][1]);
                acc[1][2] = fmaf(a1, w.z, acc[1][2]); acc[1][3] = fmaf(a1, w.w, acc[1][3]);
                acc[2][0] = fmaf(a2, w.x, acc[2][0]); acc[2][1] = fmaf(a2, w.y, acc[2][1]);
                acc[2][2] = fmaf(a2, w.z, acc[2][2]); acc[2][3] = fmaf(a2, w.w, acc[2][3]);
                acc[3][0] = fmaf(a3, w.x, acc[3][0]); acc[3][1] = fmaf(a3, w.y, acc[3][1]);
                acc[3][2] = fmaf(a3, w.z, acc[3][2]); acc[3][3] = fmaf(a3, w.w, acc[3][3]);
            }
        }
    }
    #pragma unroll
    for (int i = 0; i < 4; ++i) {
        int r = row0 + tr + i;
        if (r < N)
            *(float4*)(h + (size_t)r * 64 + tc) =
                make_float4(acc[i][0], acc[i][1], acc[i][2], acc[i][3]);
    }
    // fused s1/d1: cols [tc,tc+3] lie inside head tc>>3; pair (t^1) completes it.
    const float as0 = a_s[tc + 0], as1v = a_s[tc + 1], as2v = a_s[tc + 2], as3 = a_s[tc + 3];
    const float ad0 = a_d[tc + 0], ad1v = a_d[tc + 1], ad2v = a_d[tc + 2], ad3 = a_d[tc + 3];
    #pragma unroll
    for (int i = 0; i < 4; ++i) {
        float ps = acc[i][0] * as0 + acc[i][1] * as1v + acc[i][2] * as2v + acc[i][3] * as3;
        float pd = acc[i][0] * ad0 + acc[i][1] * ad1v + acc[i][2] * ad2v + acc[i][3] * ad3;
        ps += __shfl_xor(ps, 1);
        pd += __shfl_xor(pd, 1);
        int r = row0 + tr + i;
        if ((t & 1) == 0 && r < N) {
            int hh = (t & 15) >> 1;
            s1[r * 8 + hh] = ps;
            d1[r * 8 + hh] = pd;
        }
    }
}

// --------------- final GEMM: out = u [N,64] x W2 [64,128] + b2 -------------
// 32x128 tile, 4x4 register block/thread (reverted from fused epilogue).
__global__ __launch_bounds__(256) void k_gemm_out(const float* __restrict__ u,
                                                  const float* __restrict__ W,
                                                  const float* __restrict__ bias,
                                                  float* __restrict__ out, int N) {
    __shared__ float Ws[64 * 128];   // 32 KB
    __shared__ float xs[32][68];
    const int t = threadIdx.x;
    for (int i = t; i < 64 * 128; i += 256) Ws[i] = W[i];
    const int row0 = blockIdx.x * 32;
    for (int i = t; i < 512; i += 256) {            // 32 rows x 16 float4
        int r = i >> 4, c = i & 15;
        float4 v = make_float4(0.f, 0.f, 0.f, 0.f);
        if (row0 + r < N)
            v = *(const float4*)(u + (size_t)(row0 + r) * 64 + c * 4);
        *(float4*)&xs[r][c * 4] = v;
    }
    __syncthreads();
    const int tc = (t & 31) * 4;    // 32 col groups
    const int tr = (t >> 5) * 4;    // 8 row groups
    float acc[4][4] = {};
    #pragma unroll 4
    for (int k = 0; k < 64; k += 4) {
        const float4 xv0 = *(const float4*)&xs[tr + 0][k];
        const float4 xv1 = *(const float4*)&xs[tr + 1][k];
        const float4 xv2 = *(const float4*)&xs[tr + 2][k];
        const float4 xv3 = *(const float4*)&xs[tr + 3][k];
        #pragma unroll
        for (int kk = 0; kk < 4; ++kk) {
            const float4 w = *(const float4*)&Ws[(k + kk) * 128 + tc];
            const float a0 = (&xv0.x)[kk], a1 = (&xv1.x)[kk];
            const float a2 = (&xv2.x)[kk], a3 = (&xv3.x)[kk];
            acc[0][0] = fmaf(a0, w.x, acc[0][0]); acc[0][1] = fmaf(a0, w.y, acc[0][1]);
            acc[0][2] = fmaf(a0, w.z, acc[0][2]); acc[0][3] = fmaf(a0, w.w, acc[0][3]);
            acc[1][0] = fmaf(a1, w.x, acc[1][0]); acc[1][1] = fmaf(a1, w.y, acc[1][1]);
            acc[1][2] = fmaf(a1, w.z, acc[1][2]); acc[1][3] = fmaf(a1, w.w, acc[1][3]);
            acc[2][0] = fmaf(a2, w.x, acc[2][0]); acc[2][1] = fmaf(a2, w.y, acc[2][1]);
            acc[2][2] = fmaf(a2, w.z, acc[2][2]); acc[2][3] = fmaf(a2, w.w, acc[2][3]);
            acc[3][0] = fmaf(a3, w.x, acc[3][0]); acc[3][1] = fmaf(a3, w.y, acc[3][1]);
            acc[3][2] = fmaf(a3, w.z, acc[3][2]); acc[3][3] = fmaf(a3, w.w, acc[3][3]);
        }
    }
    const float4 bv = *(const float4*)(bias + tc);
    #pragma unroll
    for (int i = 0; i < 4; ++i) {
        int r = row0 + tr + i;
        if (r < N)
            *(float4*)(out + (size_t)r * 128 + tc) =
                make_float4(acc[i][0] + bv.x, acc[i][1] + bv.y,
                            acc[i][2] + bv.z, acc[i][3] + bv.w);
    }
}

// ------------------- layer-1 aggregation (8 heads x 8 dims) ----------------
// One wave per destination node. sched_barrier(0)-fenced load batch: the
// scheduler may NOT sink the 8 gather loads into the fma chain.
__global__ __launch_bounds__(256) void k_agg1(const float* __restrict__ h1,
                                              const float* __restrict__ s1,
                                              const float* __restrict__ d1,
                                              const int* __restrict__ offs,
                                              const int* __restrict__ srcs,
                                              const float* __restrict__ bias,
                                              const float* __restrict__ w2as,
                                              const float* __restrict__ w2ad,
                                              float* __restrict__ out,
                                              float* __restrict__ s2,
                                              float* __restrict__ d2, int N) {
    int wid = (blockIdx.x * 256 + threadIdx.x) >> 6;
    int lane = threadIdx.x & 63;
    if (wid >= N) return;
    const int beg = offs[wid], end = offs[wid + 1];
    const int slot = lane >> 3;        // staging: edge slot (8 per group)
    const int hl = lane & 7;           // staging: head
    const int c = lane & 31;           // gather: col pair {2c,2c+1}
    const int half = lane >> 5;        // gather: which edge of a pair
    const int hc = c >> 2;             // head containing cols {2c,2c+1}
    const float dt = d1[wid * 8 + hl];
    float accx = 0.f, accy = 0.f, dsum = 0.f;
    int sa = 0, sb = 0; float exa = 0.f, exb = 0.f;
    if (beg + slot < end)     { sa = srcs[beg + slot];     exa = __expf(lrelu(s1[sa * 8 + hl] + dt)); }
    if (beg + 8 + slot < end) { sb = srcs[beg + 8 + slot]; exb = __expf(lrelu(s1[sb * 8 + hl] + dt)); }
    for (int cb = beg; cb < end; cb += 16) {
        int sna = 0, snb = 0; float exna = 0.f, exnb = 0.f;
        if (cb + 16 + slot < end) { sna = srcs[cb + 16 + slot]; exna = __expf(lrelu(s1[sna * 8 + hl] + dt)); }
        if (cb + 24 + slot < end) { snb = srcs[cb + 24 + slot]; exnb = __expf(lrelu(s1[snb * 8 + hl] + dt)); }
        dsum += exa + exb;
        // phase 1: all cross-lane broadcasts
        int ssA[4], ssB[4]; float eA[4], eB[4];
        #pragma unroll
        for (int p = 0; p < 4; ++p) {
            const int sl = (2 * p + half) * 8;
            eA[p] = __shfl(exa, sl + hc);  ssA[p] = __shfl(sa, sl);
            eB[p] = __shfl(exb, sl + hc);  ssB[p] = __shfl(sb, sl);
        }
        // phase 2: 8 independent gather loads -- fenced so they all issue
        float2 hA[4], hB[4];
        __builtin_amdgcn_sched_barrier(0);
        #pragma unroll
        for (int p = 0; p < 4; ++p) {
            hA[p] = *(const float2*)(h1 + (size_t)ssA[p] * 64 + 2 * c);
            hB[p] = *(const float2*)(h1 + (size_t)ssB[p] * 64 + 2 * c);
        }
        __builtin_amdgcn_sched_barrier(0);
        // phase 3: accumulate
        #pragma unroll
        for (int p = 0; p < 4; ++p) {
            accx = fmaf(hA[p].x, eA[p], accx); accy = fmaf(hA[p].y, eA[p], accy);
            accx = fmaf(hB[p].x, eB[p], accx); accy = fmaf(hB[p].y, eB[p], accy);
        }
        sa = sna; exa = exna; sb = snb; exb = exnb;
    }
    accx += __shfl_xor(accx, 32);
    accy += __shfl_xor(accy, 32);
    dsum += __shfl_xor(dsum, 8);
    dsum += __shfl_xor(dsum, 16);
    dsum += __shfl_xor(dsum, 32);
    const float denom = __shfl(dsum, hc);
    float ox = 0.f, oy = 0.f;
    if (half == 0) {
        const float2 bv = *(const float2*)(bias + 2 * c);
        ox = fmaxf(accx / denom + bv.x, 0.f);    // fused inter-layer ReLU
        oy = fmaxf(accy / denom + bv.y, 0.f);
        *(float2*)(out + (size_t)wid * 64 + 2 * c) = make_float2(ox, oy);
    }
    // layer-2 logit terms: s2 = row . w2as, d2 = row . w2ad
    float ps = 0.f, pd = 0.f;
    if (half == 0) {
        const float2 was = *(const float2*)(w2as + 2 * c);
        const float2 wad = *(const float2*)(w2ad + 2 * c);
        ps = ox * was.x + oy * was.y;
        pd = ox * wad.x + oy * wad.y;
    }
    #pragma unroll
    for (int mask = 1; mask < 32; mask <<= 1) {
        ps += __shfl_xor(ps, mask);
        pd += __shfl_xor(pd, mask);
    }
    if (lane == 0) { s2[wid] = ps; d2[wid] = pd; }
}

// ------------- layer-2 aggregation over hrelu (64 dims, pre-W2) ------------
// One wave per destination node; sched_barrier(0)-fenced 8-deep load batch.
__global__ __launch_bounds__(256) void k_agg2(const float* __restrict__ hrelu,
                                              const float* __restrict__ s2,
                                              const float* __restrict__ d2,
                                              const int* __restrict__ offs,
                                              const int* __restrict__ srcs,
                                              float* __restrict__ u, int N) {
    int wid = (blockIdx.x * 256 + threadIdx.x) >> 6;
    int lane = threadIdx.x & 63;
    if (wid >= N) return;
    const int beg = offs[wid], end = offs[wid + 1];
    const int c = lane & 31;
    const int half = lane >> 5;
    const float dn = d2[wid];
    float accx = 0.f, accy = 0.f, dsum = 0.f;
    int s_cur = 0; float ex_cur = 0.f;
    if (beg + lane < end) {
        s_cur = srcs[beg + lane];
        ex_cur = __expf(lrelu(s2[s_cur] + dn));            // no max-shift
    }
    for (int cb = beg; cb < end; cb += 64) {
        int sn = 0; float exn = 0.f;
        if (cb + 64 + lane < end) { sn = srcs[cb + 64 + lane]; exn = __expf(lrelu(s2[sn] + dn)); }
        dsum += ex_cur;
        const int npairs = (min(64, end - cb) + 1) >> 1;
        for (int p0 = 0; p0 < npairs; p0 += 8) {
            // phase 1: broadcasts
            int ss[8]; float e[8];
            #pragma unroll
            for (int q = 0; q < 8; ++q) {
                const int sl = min(2 * (p0 + q) + half, 63);  // padded slots have ex=0
                e[q] = __shfl(ex_cur, sl);
                ss[q] = __shfl(s_cur, sl);
            }
            // phase 2: 8 independent loads -- fenced
            float2 hv[8];
            __builtin_amdgcn_sched_barrier(0);
            #pragma unroll
            for (int q = 0; q < 8; ++q)
                hv[q] = *(const float2*)(hrelu + (size_t)ss[q] * 64 + 2 * c);
            __builtin_amdgcn_sched_barrier(0);
            // phase 3: accumulate
            #pragma unroll
            for (int q = 0; q < 8; ++q) {
                accx = fmaf(hv[q].x, e[q], accx);
                accy = fmaf(hv[q].y, e[q], accy);
            }
        }
        s_cur = sn; ex_cur = exn;
    }
    accx += __shfl_xor(accx, 32);
    accy += __shfl_xor(accy, 32);
    #pragma unroll
    for (int mask = 1; mask < 64; mask <<= 1) dsum += __shfl_xor(dsum, mask);
    if (half == 0) {
        const float inv = 1.f / dsum;
        *(float2*)(u + (size_t)wid * 64 + 2 * c) = make_float2(accx * inv, accy * inv);
    }
}

// ---------------------------------------------------------------------------

extern "C" void kernel_launch(void* const* d_in, const int* in_sizes, int n_in,
                              void* d_out, int out_size, void* d_ws, size_t ws_size,
                              hipStream_t stream) {
    const float* x   = (const float*)d_in[0];
    const int*   ei  = (const int*)d_in[1];
    const float* W1  = (const float*)d_in[2];
    const float* as1 = (const float*)d_in[3];
    const float* ad1 = (const float*)d_in[4];
    const float* b1  = (const float*)d_in[5];
    const float* W2  = (const float*)d_in[6];
    const float* as2 = (const float*)d_in[7];
    const float* ad2 = (const float*)d_in[8];
    const float* b2  = (const float*)d_in[9];
    float* out = (float*)d_out;

    const int N = in_sizes[0] / 128;   // 100000
    const int E = in_sizes[1] / 2;     // 1700000
    const int* srcp = ei;
    const int* dstp = ei + E;

    const int SB  = (E + SORT_EPB - 1) / SORT_EPB;   // sort blocks (416)
    const int NB2 = (N + 511) >> 9;                  // high-bit buckets (196)
    const int L   = NB2 * SB;                        // counts length

    // workspace carve-out (aligned to 256B)
    char* w = (char*)d_ws;
    auto carve = [&](size_t bytes) -> char* {
        char* p = w;
        w += (bytes + 255) & ~(size_t)255;
        return p;
    };
    float* h1    = (float*)carve((size_t)N * 64 * 4);
    float* hrelu = (float*)carve((size_t)N * 64 * 4);
    float* u     = (float*)carve((size_t)N * 64 * 4);
    float* s1    = (float*)carve((size_t)N * 8 * 4);
    float* d1    = (float*)carve((size_t)N * 8 * 4);
    float* s2    = (float*)carve((size_t)N * 4);
    float* d2    = (float*)carve((size_t)N * 4);
    float* w2as  = (float*)carve(64 * 4);
    float* w2ad  = (float*)carve(64 * 4);
    int*   offs  = (int*)carve((size_t)(N + 1) * 4);
    int*   counts= (int*)carve((size_t)(L + 1) * 4);
    const int BS = (L + 1023) / 1024;                // scan blocks for counts
    int*   bsum  = (int*)carve((size_t)BS * 4);
    int*   packed= (int*)carve((size_t)E * 4);
    int*   srcs  = (int*)carve((size_t)E * 4);
    (void)ws_size; (void)n_in; (void)out_size;

    const int TB = 256;
    // --- CSR build: LDS-atomic bucket sort (no global atomics) + w2a tail ---
    hipLaunchKernelGGL(k_hist,           dim3(SB + 1), dim3(TB), 0, stream,
                       dstp, counts, E, SB, NB2, W2, as2, ad2, w2as, w2ad);
    hipLaunchKernelGGL(k_scan_blocks,    dim3(BS), dim3(TB), 0, stream, counts, counts, bsum, L);
    hipLaunchKernelGGL(k_scan_tops,      dim3(1),  dim3(TB), 0, stream, bsum, BS);
    hipLaunchKernelGGL(k_scan_add,       dim3((L + TB - 1) / TB), dim3(TB), 0, stream, counts, bsum, L, E);
    hipLaunchKernelGGL(k_bucket_scatter, dim3(SB), dim3(TB), 0, stream, srcp, dstp, counts, packed, E, SB, NB2);
    hipLaunchKernelGGL(k_bucket_sort,    dim3(NB2), dim3(TB), 0, stream, packed, counts, srcs, offs, E, SB, N);
    // --- layer 1 ---
    hipLaunchKernelGGL(k_gemm1, dim3((N + 63) / 64), dim3(TB), 0, stream, x, W1, as1, ad1, h1, s1, d1, N);
    hipLaunchKernelGGL(k_agg1,  dim3((N + 3) / 4),   dim3(TB), 0, stream,
                       h1, s1, d1, offs, srcs, b1, w2as, w2ad, hrelu, s2, d2, N);
    // --- layer 2: aggregate hrelu, then GEMM ---
    hipLaunchKernelGGL(k_agg2,     dim3((N + 3) / 4),   dim3(TB), 0, stream, hrelu, s2, d2, offs, srcs, u, N);
    hipLaunchKernelGGL(k_gemm_out, dim3((N + 31) / 32), dim3(TB), 0, stream, u, W2, b2, out, N);
}

// Round 11
// 343.903 us; speedup vs baseline: 1.2744x; 1.1522x over previous
//
#include <hip/hip_runtime.h>
#include <hip/hip_fp16.h>
#include <math.h>

// ---------------------------------------------------------------------------
// 2-layer GAT (PyG GATConv semantics) on MI355X.
// R6:  CSR via LDS-atomic bucket sort (no global atomics).
// R5:  layer-2 commuted with W2 (aggregate 64-dim hrelu).
// R11: h1/hrelu stored as FP16 (arithmetic stays f32) -- halves the random
//      gather bytes that bound both aggregation kernels; sched_barrier fences
//      removed (R10: they blocked staging-load hoisting, +8us).
// ---------------------------------------------------------------------------

#define SORT_EPB 4096   // edges per hist/scatter block (256 thr x 16)

static __device__ __forceinline__ float lrelu(float v) {
    return v > 0.f ? v : 0.2f * v;
}

// ----------------------------- scan machinery ------------------------------
// Block-level exclusive scan: each block scans 1024 elements (4/thread).
__global__ __launch_bounds__(256) void k_scan_blocks(const int* __restrict__ deg,
                                                     int* __restrict__ offs,
                                                     int* __restrict__ bsum, int N) {
    __shared__ int ls[256];
    const int t = threadIdx.x;
    const int base = blockIdx.x * 1024 + t * 4;
    int v0 = (base + 0 < N) ? deg[base + 0] : 0;
    int v1 = (base + 1 < N) ? deg[base + 1] : 0;
    int v2 = (base + 2 < N) ? deg[base + 2] : 0;
    int v3 = (base + 3 < N) ? deg[base + 3] : 0;
    const int sum = v0 + v1 + v2 + v3;
    int val = sum;
    ls[t] = val;
    __syncthreads();
    for (int off = 1; off < 256; off <<= 1) {
        int x = (t >= off) ? ls[t - off] : 0;
        __syncthreads();
        val += x;
        ls[t] = val;
        __syncthreads();
    }
    int run = val - sum;  // exclusive prefix of this thread's chunk
    if (base + 0 < N) offs[base + 0] = run;  run += v0;
    if (base + 1 < N) offs[base + 1] = run;  run += v1;
    if (base + 2 < N) offs[base + 2] = run;  run += v2;
    if (base + 3 < N) offs[base + 3] = run;
    if (t == 255) bsum[blockIdx.x] = val;    // block total
}

// Parallel exclusive scan of block sums (B <= 256).
__global__ __launch_bounds__(256) void k_scan_tops(int* __restrict__ bsum, int B) {
    __shared__ int ls[256];
    const int t = threadIdx.x;
    int v = (t < B) ? bsum[t] : 0;
    int val = v;
    ls[t] = val;
    __syncthreads();
    for (int off = 1; off < 256; off <<= 1) {
        int x = (t >= off) ? ls[t - off] : 0;
        __syncthreads();
        val += x;
        ls[t] = val;
        __syncthreads();
    }
    if (t < B) bsum[t] = val - v;            // exclusive
}

__global__ __launch_bounds__(256) void k_scan_add(int* __restrict__ offs,
                                                  const int* __restrict__ bsum,
                                                  int N, int E) {
    int i = blockIdx.x * 256 + threadIdx.x;
    if (i < N) offs[i] = offs[i] + bsum[i >> 10];
    if (i == 0) offs[N] = E;                 // sentinel
}

// ----------------------- bucket-sort CSR build (LDS only) ------------------
// Pass A: per-block histogram of high bits (dst>>9), NB2 bins (<=256).
// Extra tail block (blockIdx == SB) computes w2as/w2ad = W2 @ a_s2 / a_d2.
__global__ __launch_bounds__(256) void k_hist(const int* __restrict__ dst,
                                              int* __restrict__ counts,
                                              int E, int B, int NB2,
                                              const float* __restrict__ W2,
                                              const float* __restrict__ as2,
                                              const float* __restrict__ ad2,
                                              float* __restrict__ w2as,
                                              float* __restrict__ w2ad) {
    const int t = threadIdx.x;
    const int b = blockIdx.x;
    if (b == B) {                            // tiny w2a precompute
        if (t < 64) {
            const float* row = W2 + t * 128;
            float s = 0.f, d = 0.f;
            #pragma unroll 8
            for (int j = 0; j < 128; ++j) { s = fmaf(row[j], as2[j], s); d = fmaf(row[j], ad2[j], d); }
            w2as[t] = s; w2ad[t] = d;
        }
        return;
    }
    __shared__ int h[256];
    h[t] = 0;
    __syncthreads();
    const int base_i = b * SORT_EPB;
    #pragma unroll 4
    for (int k = 0; k < 16; ++k) {
        int i = base_i + k * 256 + t;
        if (i < E) atomicAdd(&h[dst[i] >> 9], 1);
    }
    __syncthreads();
    if (t < NB2) counts[t * B + b] = h[t];   // bin-major
}

// Pass B: scatter edges into bucket order; pack (src<<9)|(dst&511).
__global__ __launch_bounds__(256) void k_bucket_scatter(const int* __restrict__ src,
                                                        const int* __restrict__ dst,
                                                        const int* __restrict__ base,
                                                        int* __restrict__ packed,
                                                        int E, int B, int NB2) {
    __shared__ int cur[256];
    const int t = threadIdx.x;
    const int b = blockIdx.x;
    if (t < NB2) cur[t] = base[t * B + b];
    __syncthreads();
    const int base_i = b * SORT_EPB;
    #pragma unroll 4
    for (int k = 0; k < 16; ++k) {
        int i = base_i + k * 256 + t;
        if (i < E) {
            int d = dst[i];
            int pos = atomicAdd(&cur[d >> 9], 1);
            packed[pos] = (src[i] << 9) | (d & 511);
        }
    }
}

// Pass C: per-bucket counting sort (512 nodes/bucket); emits srcs + offs.
__global__ __launch_bounds__(256) void k_bucket_sort(const int* __restrict__ packed,
                                                     const int* __restrict__ base,
                                                     int* __restrict__ srcs,
                                                     int* __restrict__ offs,
                                                     int E, int B, int N) {
    __shared__ int h[512], sc[512], cur[512], ls[256];
    const int t = threadIdx.x;
    const int j = blockIdx.x;
    const int bstart = base[j * B];
    const int bend   = base[(j + 1) * B];    // sentinel handles last bucket
    h[t] = 0; h[t + 256] = 0;
    __syncthreads();
    for (int i = bstart + t; i < bend; i += 256)
        atomicAdd(&h[packed[i] & 511], 1);
    __syncthreads();
    // exclusive scan of 512 bins: thread t owns bins {2t, 2t+1}
    const int a0 = h[2 * t], a1 = h[2 * t + 1];
    int val = a0 + a1;
    ls[t] = val;
    __syncthreads();
    for (int off = 1; off < 256; off <<= 1) {
        int x = (t >= off) ? ls[t - off] : 0;
        __syncthreads();
        val += x;
        ls[t] = val;
        __syncthreads();
    }
    const int pre = val - (a0 + a1);
    sc[2 * t] = pre;         sc[2 * t + 1] = pre + a0;
    cur[2 * t] = pre;        cur[2 * t + 1] = pre + a0;
    __syncthreads();
    // offs: node = j*512 + bin (bijective within bucket; self-loops => dense)
    const int node0 = j * 512 + 2 * t;
    if (node0 < N)     offs[node0]     = bstart + sc[2 * t];
    if (node0 + 1 < N) offs[node0 + 1] = bstart + sc[2 * t + 1];
    if (j == 0 && t == 0) offs[N] = E;
    // scatter within bucket (order within node-segment is arbitrary: OK)
    for (int i = bstart + t; i < bend; i += 256) {
        int p = packed[i];
        int pos = atomicAdd(&cur[p & 511], 1);
        srcs[bstart + pos] = p >> 9;
    }
}

// ----------------------------- GEMM 1: [N,128]x[128,64] --------------------
// 64x64 tile, 4x4 register block/thread; fused s1/d1 epilogue.
// h output stored FP16 (arithmetic f32).
__global__ __launch_bounds__(256) void k_gemm1(const float* __restrict__ x,
                                               const float* __restrict__ W,
                                               const float* __restrict__ a_s,
                                               const float* __restrict__ a_d,
                                               __half* __restrict__ h,
                                               float* __restrict__ s1,
                                               float* __restrict__ d1, int N) {
    __shared__ float Ws[128 * 64];   // 32 KB, full W
    __shared__ float xs[64][68];
    const int t = threadIdx.x;
    for (int i = t; i < 128 * 64; i += 256) Ws[i] = W[i];
    const int row0 = blockIdx.x * 64;
    const int tc = (t & 15) * 4;    // 16 col groups
    const int tr = (t >> 4) * 4;    // 16 row groups
    float acc[4][4] = {};
    for (int kb = 0; kb < 128; kb += 64) {
        if (kb) __syncthreads();
        for (int i = t; i < 1024; i += 256) {       // 64 rows x 16 float4
            int r = i >> 4, c = i & 15;
            float4 v = make_float4(0.f, 0.f, 0.f, 0.f);
            if (row0 + r < N)
                v = *(const float4*)(x + (size_t)(row0 + r) * 128 + kb + c * 4);
            *(float4*)&xs[r][c * 4] = v;
        }
        __syncthreads();
        #pragma unroll 4
        for (int k = 0; k < 64; k += 4) {
            const float4 xv0 = *(const float4*)&xs[tr + 0][k];
            const float4 xv1 = *(const float4*)&xs[tr + 1][k];
            const float4 xv2 = *(const float4*)&xs[tr + 2][k];
            const float4 xv3 = *(const float4*)&xs[tr + 3][k];
            #pragma unroll
            for (int kk = 0; kk < 4; ++kk) {
                const float4 w = *(const float4*)&Ws[(kb + k + kk) * 64 + tc];
                const float a0 = (&xv0.x)[kk], a1 = (&xv1.x)[kk];
                const float a2 = (&xv2.x)[kk], a3 = (&xv3.x)[kk];
                acc[0][0] = fmaf(a0, w.x, acc[0][0]); acc[0][1] = fmaf(a0, w.y, acc[0][1]);
                acc[0][2] = fmaf(a0, w.z, acc[0][2]); acc[0][3] = fmaf(a0, w.w, acc[0][3]);
                acc[1][0] = fmaf(a1, w.x, acc[1][0]); acc[1][1] = fmaf(a1, w.y, acc[1][1]);
                acc[1][2] = fmaf(a1, w.z, acc[1][2]); acc[1][3] = fmaf(a1, w.w, acc[1][3]);
                acc[2][0] = fmaf(a2, w.x, acc[2][0]); acc[2][1] = fmaf(a2, w.y, acc[2][1]);
                acc[2][2] = fmaf(a2, w.z, acc[2][2]); acc[2][3] = fmaf(a2, w.w, acc[2][3]);
                acc[3][0] = fmaf(a3, w.x, acc[3][0]); acc[3][1] = fmaf(a3, w.y, acc[3][1]);
                acc[3][2] = fmaf(a3, w.z, acc[3][2]); acc[3][3] = fmaf(a3, w.w, acc[3][3]);
            }
        }
    }
    #pragma unroll
    for (int i = 0; i < 4; ++i) {
        int r = row0 + tr + i;
        if (r < N) {
            union { __half2 h2[2]; float2 f2; } cvt;
            cvt.h2[0] = __floats2half2_rn(acc[i][0], acc[i][1]);
            cvt.h2[1] = __floats2half2_rn(acc[i][2], acc[i][3]);
            *(float2*)(h + (size_t)r * 64 + tc) = cvt.f2;   // 8B store
        }
    }
    // fused s1/d1: cols [tc,tc+3] lie inside head tc>>3; pair (t^1) completes it.
    const float as0 = a_s[tc + 0], as1v = a_s[tc + 1], as2v = a_s[tc + 2], as3 = a_s[tc + 3];
    const float ad0 = a_d[tc + 0], ad1v = a_d[tc + 1], ad2v = a_d[tc + 2], ad3 = a_d[tc + 3];
    #pragma unroll
    for (int i = 0; i < 4; ++i) {
        float ps = acc[i][0] * as0 + acc[i][1] * as1v + acc[i][2] * as2v + acc[i][3] * as3;
        float pd = acc[i][0] * ad0 + acc[i][1] * ad1v + acc[i][2] * ad2v + acc[i][3] * ad3;
        ps += __shfl_xor(ps, 1);
        pd += __shfl_xor(pd, 1);
        int r = row0 + tr + i;
        if ((t & 1) == 0 && r < N) {
            int hh = (t & 15) >> 1;
            s1[r * 8 + hh] = ps;
            d1[r * 8 + hh] = pd;
        }
    }
}

// --------------- final GEMM: out = u [N,64] x W2 [64,128] + b2 -------------
// 32x128 tile, 4x4 register block/thread.
__global__ __launch_bounds__(256) void k_gemm_out(const float* __restrict__ u,
                                                  const float* __restrict__ W,
                                                  const float* __restrict__ bias,
                                                  float* __restrict__ out, int N) {
    __shared__ float Ws[64 * 128];   // 32 KB
    __shared__ float xs[32][68];
    const int t = threadIdx.x;
    for (int i = t; i < 64 * 128; i += 256) Ws[i] = W[i];
    const int row0 = blockIdx.x * 32;
    for (int i = t; i < 512; i += 256) {            // 32 rows x 16 float4
        int r = i >> 4, c = i & 15;
        float4 v = make_float4(0.f, 0.f, 0.f, 0.f);
        if (row0 + r < N)
            v = *(const float4*)(u + (size_t)(row0 + r) * 64 + c * 4);
        *(float4*)&xs[r][c * 4] = v;
    }
    __syncthreads();
    const int tc = (t & 31) * 4;    // 32 col groups
    const int tr = (t >> 5) * 4;    // 8 row groups
    float acc[4][4] = {};
    #pragma unroll 4
    for (int k = 0; k < 64; k += 4) {
        const float4 xv0 = *(const float4*)&xs[tr + 0][k];
        const float4 xv1 = *(const float4*)&xs[tr + 1][k];
        const float4 xv2 = *(const float4*)&xs[tr + 2][k];
        const float4 xv3 = *(const float4*)&xs[tr + 3][k];
        #pragma unroll
        for (int kk = 0; kk < 4; ++kk) {
            const float4 w = *(const float4*)&Ws[(k + kk) * 128 + tc];
            const float a0 = (&xv0.x)[kk], a1 = (&xv1.x)[kk];
            const float a2 = (&xv2.x)[kk], a3 = (&xv3.x)[kk];
            acc[0][0] = fmaf(a0, w.x, acc[0][0]); acc[0][1] = fmaf(a0, w.y, acc[0][1]);
            acc[0][2] = fmaf(a0, w.z, acc[0][2]); acc[0][3] = fmaf(a0, w.w, acc[0][3]);
            acc[1][0] = fmaf(a1, w.x, acc[1][0]); acc[1][1] = fmaf(a1, w.y, acc[1][1]);
            acc[1][2] = fmaf(a1, w.z, acc[1][2]); acc[1][3] = fmaf(a1, w.w, acc[1][3]);
            acc[2][0] = fmaf(a2, w.x, acc[2][0]); acc[2][1] = fmaf(a2, w.y, acc[2][1]);
            acc[2][2] = fmaf(a2, w.z, acc[2][2]); acc[2][3] = fmaf(a2, w.w, acc[2][3]);
            acc[3][0] = fmaf(a3, w.x, acc[3][0]); acc[3][1] = fmaf(a3, w.y, acc[3][1]);
            acc[3][2] = fmaf(a3, w.z, acc[3][2]); acc[3][3] = fmaf(a3, w.w, acc[3][3]);
        }
    }
    const float4 bv = *(const float4*)(bias + tc);
    #pragma unroll
    for (int i = 0; i < 4; ++i) {
        int r = row0 + tr + i;
        if (r < N)
            *(float4*)(out + (size_t)r * 128 + tc) =
                make_float4(acc[i][0] + bv.x, acc[i][1] + bv.y,
                            acc[i][2] + bv.z, acc[i][3] + bv.w);
    }
}

// ------------------- layer-1 aggregation (8 heads x 8 dims) ----------------
// One wave per destination node; fp16 h1 gather (dword/lane, 2 edges/instr
// via wave halves), R7-style inline loop (no sched fences).
__global__ __launch_bounds__(256) void k_agg1(const __half* __restrict__ h1,
                                              const float* __restrict__ s1,
                                              const float* __restrict__ d1,
                                              const int* __restrict__ offs,
                                              const int* __restrict__ srcs,
                                              const float* __restrict__ bias,
                                              const float* __restrict__ w2as,
                                              const float* __restrict__ w2ad,
                                              __half* __restrict__ out,
                                              float* __restrict__ s2,
                                              float* __restrict__ d2, int N) {
    int wid = (blockIdx.x * 256 + threadIdx.x) >> 6;
    int lane = threadIdx.x & 63;
    if (wid >= N) return;
    const int beg = offs[wid], end = offs[wid + 1];
    const int slot = lane >> 3;        // staging: edge slot (8 per group)
    const int hl = lane & 7;           // staging: head
    const int c = lane & 31;           // gather: col pair {2c,2c+1}
    const int half2_ = lane >> 5;      // gather: which edge of a pair
    const int hc = c >> 2;             // head containing cols {2c,2c+1}
    const float dt = d1[wid * 8 + hl];
    float accx = 0.f, accy = 0.f, dsum = 0.f;
    int sa = 0, sb = 0; float exa = 0.f, exb = 0.f;
    if (beg + slot < end)     { sa = srcs[beg + slot];     exa = __expf(lrelu(s1[sa * 8 + hl] + dt)); }
    if (beg + 8 + slot < end) { sb = srcs[beg + 8 + slot]; exb = __expf(lrelu(s1[sb * 8 + hl] + dt)); }
    for (int cb = beg; cb < end; cb += 16) {
        int sna = 0, snb = 0; float exna = 0.f, exnb = 0.f;
        if (cb + 16 + slot < end) { sna = srcs[cb + 16 + slot]; exna = __expf(lrelu(s1[sna * 8 + hl] + dt)); }
        if (cb + 24 + slot < end) { snb = srcs[cb + 24 + slot]; exnb = __expf(lrelu(s1[snb * 8 + hl] + dt)); }
        dsum += exa + exb;
        #pragma unroll
        for (int p = 0; p < 4; ++p) {
            const int sl = (2 * p + half2_) * 8;
            const float e0 = __shfl(exa, sl + hc);
            const int  ss0 = __shfl(sa, sl);
            const float e1 = __shfl(exb, sl + hc);
            const int  ss1 = __shfl(sb, sl);
            const float2 hv0 = __half22float2(*(const __half2*)(h1 + (size_t)ss0 * 64 + 2 * c));
            const float2 hv1 = __half22float2(*(const __half2*)(h1 + (size_t)ss1 * 64 + 2 * c));
            accx = fmaf(hv0.x, e0, accx); accy = fmaf(hv0.y, e0, accy);
            accx = fmaf(hv1.x, e1, accx); accy = fmaf(hv1.y, e1, accy);
        }
        sa = sna; exa = exna; sb = snb; exb = exnb;
    }
    // combine wave halves (two edge streams, same cols)
    accx += __shfl_xor(accx, 32);
    accy += __shfl_xor(accy, 32);
    // denom: reduce over slot bits; lane hc holds denom of head hc
    dsum += __shfl_xor(dsum, 8);
    dsum += __shfl_xor(dsum, 16);
    dsum += __shfl_xor(dsum, 32);
    const float denom = __shfl(dsum, hc);
    float ox = 0.f, oy = 0.f;
    if (half2_ == 0) {
        const float2 bv = *(const float2*)(bias + 2 * c);
        ox = fmaxf(accx / denom + bv.x, 0.f);    // fused inter-layer ReLU
        oy = fmaxf(accy / denom + bv.y, 0.f);
        *(__half2*)(out + (size_t)wid * 64 + 2 * c) = __floats2half2_rn(ox, oy);
    }
    // layer-2 logit terms: s2 = row . w2as, d2 = row . w2ad
    float ps = 0.f, pd = 0.f;
    if (half2_ == 0) {
        const float2 was = *(const float2*)(w2as + 2 * c);
        const float2 wad = *(const float2*)(w2ad + 2 * c);
        ps = ox * was.x + oy * was.y;
        pd = ox * wad.x + oy * wad.y;
    }
    #pragma unroll
    for (int mask = 1; mask < 32; mask <<= 1) {
        ps += __shfl_xor(ps, mask);
        pd += __shfl_xor(pd, mask);
    }
    if (lane == 0) { s2[wid] = ps; d2[wid] = pd; }
}

// ------------- layer-2 aggregation over hrelu (fp16, 64 dims) --------------
// One wave per destination node; inline 8-unrolled pair loop (no fences).
__global__ __launch_bounds__(256) void k_agg2(const __half* __restrict__ hrelu,
                                              const float* __restrict__ s2,
                                              const float* __restrict__ d2,
                                              const int* __restrict__ offs,
                                              const int* __restrict__ srcs,
                                              float* __restrict__ u, int N) {
    int wid = (blockIdx.x * 256 + threadIdx.x) >> 6;
    int lane = threadIdx.x & 63;
    if (wid >= N) return;
    const int beg = offs[wid], end = offs[wid + 1];
    const int c = lane & 31;
    const int half2_ = lane >> 5;
    const float dn = d2[wid];
    float accx = 0.f, accy = 0.f, dsum = 0.f;
    int s_cur = 0; float ex_cur = 0.f;
    if (beg + lane < end) {
        s_cur = srcs[beg + lane];
        ex_cur = __expf(lrelu(s2[s_cur] + dn));            // no max-shift
    }
    for (int cb = beg; cb < end; cb += 64) {
        int sn = 0; float exn = 0.f;
        if (cb + 64 + lane < end) { sn = srcs[cb + 64 + lane]; exn = __expf(lrelu(s2[sn] + dn)); }
        dsum += ex_cur;
        const int npairs = (min(64, end - cb) + 1) >> 1;
        for (int p0 = 0; p0 < npairs; p0 += 8) {
            #pragma unroll
            for (int q = 0; q < 8; ++q) {
                const int sl = min(2 * (p0 + q) + half2_, 63);  // padded slots have ex=0
                const float e = __shfl(ex_cur, sl);
                const int ss = __shfl(s_cur, sl);
                const float2 hv = __half22float2(*(const __half2*)(hrelu + (size_t)ss * 64 + 2 * c));
                accx = fmaf(hv.x, e, accx);
                accy = fmaf(hv.y, e, accy);
            }
        }
        s_cur = sn; ex_cur = exn;
    }
    accx += __shfl_xor(accx, 32);
    accy += __shfl_xor(accy, 32);
    #pragma unroll
    for (int mask = 1; mask < 64; mask <<= 1) dsum += __shfl_xor(dsum, mask);
    if (half2_ == 0) {
        const float inv = 1.f / dsum;
        *(float2*)(u + (size_t)wid * 64 + 2 * c) = make_float2(accx * inv, accy * inv);
    }
}

// ---------------------------------------------------------------------------

extern "C" void kernel_launch(void* const* d_in, const int* in_sizes, int n_in,
                              void* d_out, int out_size, void* d_ws, size_t ws_size,
                              hipStream_t stream) {
    const float* x   = (const float*)d_in[0];
    const int*   ei  = (const int*)d_in[1];
    const float* W1  = (const float*)d_in[2];
    const float* as1 = (const float*)d_in[3];
    const float* ad1 = (const float*)d_in[4];
    const float* b1  = (const float*)d_in[5];
    const float* W2  = (const float*)d_in[6];
    const float* as2 = (const float*)d_in[7];
    const float* ad2 = (const float*)d_in[8];
    const float* b2  = (const float*)d_in[9];
    float* out = (float*)d_out;

    const int N = in_sizes[0] / 128;   // 100000
    const int E = in_sizes[1] / 2;     // 1700000
    const int* srcp = ei;
    const int* dstp = ei + E;

    const int SB  = (E + SORT_EPB - 1) / SORT_EPB;   // sort blocks (416)
    const int NB2 = (N + 511) >> 9;                  // high-bit buckets (196)
    const int L   = NB2 * SB;                        // counts length

    // workspace carve-out (aligned to 256B)
    char* w = (char*)d_ws;
    auto carve = [&](size_t bytes) -> char* {
        char* p = w;
        w += (bytes + 255) & ~(size_t)255;
        return p;
    };
    __half* h1    = (__half*)carve((size_t)N * 64 * 2);
    __half* hrelu = (__half*)carve((size_t)N * 64 * 2);
    float*  u     = (float*)carve((size_t)N * 64 * 4);
    float*  s1    = (float*)carve((size_t)N * 8 * 4);
    float*  d1    = (float*)carve((size_t)N * 8 * 4);
    float*  s2    = (float*)carve((size_t)N * 4);
    float*  d2    = (float*)carve((size_t)N * 4);
    float*  w2as  = (float*)carve(64 * 4);
    float*  w2ad  = (float*)carve(64 * 4);
    int*    offs  = (int*)carve((size_t)(N + 1) * 4);
    int*    counts= (int*)carve((size_t)(L + 1) * 4);
    const int BS  = (L + 1023) / 1024;               // scan blocks for counts
    int*    bsum  = (int*)carve((size_t)BS * 4);
    int*    packed= (int*)carve((size_t)E * 4);
    int*    srcs  = (int*)carve((size_t)E * 4);
    (void)ws_size; (void)n_in; (void)out_size;

    const int TB = 256;
    // --- CSR build: LDS-atomic bucket sort (no global atomics) + w2a tail ---
    hipLaunchKernelGGL(k_hist,           dim3(SB + 1), dim3(TB), 0, stream,
                       dstp, counts, E, SB, NB2, W2, as2, ad2, w2as, w2ad);
    hipLaunchKernelGGL(k_scan_blocks,    dim3(BS), dim3(TB), 0, stream, counts, counts, bsum, L);
    hipLaunchKernelGGL(k_scan_tops,      dim3(1),  dim3(TB), 0, stream, bsum, BS);
    hipLaunchKernelGGL(k_scan_add,       dim3((L + TB - 1) / TB), dim3(TB), 0, stream, counts, bsum, L, E);
    hipLaunchKernelGGL(k_bucket_scatter, dim3(SB), dim3(TB), 0, stream, srcp, dstp, counts, packed, E, SB, NB2);
    hipLaunchKernelGGL(k_bucket_sort,    dim3(NB2), dim3(TB), 0, stream, packed, counts, srcs, offs, E, SB, N);
    // --- layer 1 ---
    hipLaunchKernelGGL(k_gemm1, dim3((N + 63) / 64), dim3(TB), 0, stream, x, W1, as1, ad1, h1, s1, d1, N);
    hipLaunchKernelGGL(k_agg1,  dim3((N + 3) / 4),   dim3(TB), 0, stream,
                       h1, s1, d1, offs, srcs, b1, w2as, w2ad, hrelu, s2, d2, N);
    // --- layer 2: aggregate hrelu, then GEMM ---
    hipLaunchKernelGGL(k_agg2,     dim3((N + 3) / 4),   dim3(TB), 0, stream, hrelu, s2, d2, offs, srcs, u, N);
    hipLaunchKernelGGL(k_gemm_out, dim3((N + 31) / 32), dim3(TB), 0, stream, u, W2, b2, out, N);
}